// Round 3
// baseline (203.215 us; speedup 1.0000x reference)
//
#include <hip/hip_runtime.h>

#define BATCH 256
#define TT 256
#define DD 384
#define HH 64
#define SCALE 0.125f

typedef __attribute__((ext_vector_type(8))) short short8;
typedef __attribute__((ext_vector_type(4))) float floatx4;

#define KS_STRIDE 72    // [T][72] bf16: row stride 144B -> 2-way bank aliasing (free)
#define VT_STRIDE 264   // [H][264] bf16: row stride 528B, 16B-aligned
#define QS_STRIDE 72    // per-wave Q scratch [32][72]
#define PS_STRIDE 40    // per-wave P scratch [32][40]: 80B rows, 16B-aligned

// f32 -> bf16 round-to-nearest-even
__device__ __forceinline__ unsigned short f2bf(float f) {
    unsigned int u = __float_as_uint(f);
    u += 0x7fffu + ((u >> 16) & 1u);
    return (unsigned short)(u >> 16);
}

// Load 8 consecutive fp32, convert to 8 bf16 packed in a short8 (one MFMA operand frag).
__device__ __forceinline__ short8 cvt8(const float* __restrict__ p) {
    float4 f0 = *(const float4*)p;
    float4 f1 = *(const float4*)(p + 4);
    short8 r;
    r[0] = (short)f2bf(f0.x); r[1] = (short)f2bf(f0.y);
    r[2] = (short)f2bf(f0.z); r[3] = (short)f2bf(f0.w);
    r[4] = (short)f2bf(f1.x); r[5] = (short)f2bf(f1.y);
    r[6] = (short)f2bf(f1.z); r[7] = (short)f2bf(f1.w);
    return r;
}

// Transpose+convert W [D][H] fp32 -> Wt [3][H][D] bf16 so B-fragments are contiguous 16B rows.
__global__ void transpose_w_kernel(const float* __restrict__ wq,
                                   const float* __restrict__ wk,
                                   const float* __restrict__ wv,
                                   unsigned short* __restrict__ wt) {
    int idx = blockIdx.x * 256 + threadIdx.x;
    if (idx >= 3 * DD * HH) return;
    int mat = idx / (DD * HH);
    int rem = idx - mat * (DD * HH);
    int d = rem / HH;
    int h = rem - d * HH;
    const float* w = (mat == 0) ? wq : (mat == 1) ? wk : wv;
    wt[(mat * HH + h) * DD + d] = f2bf(w[d * HH + h]);
}

// One block per batch element. 512 threads = 8 waves; wave w owns query rows [32w, 32w+32).
__global__ __launch_bounds__(512, 2)
void attn_kernel(const float* __restrict__ x,
                 const unsigned short* __restrict__ wt,
                 float* __restrict__ out) {
    __shared__ __align__(16) unsigned short Ks[TT * KS_STRIDE];       // 36,864 B
    __shared__ __align__(16) unsigned short Vt[HH * VT_STRIDE];       // 33,792 B
    __shared__ __align__(16) unsigned short Scr[8 * 32 * QS_STRIDE];  // 36,864 B

    const int b = blockIdx.x;
    const int tid = threadIdx.x;
    const int wave = tid >> 6;
    const int lane = tid & 63;
    const int quad = lane >> 4;
    const int l16 = lane & 15;

    const float* xb = x + (size_t)b * TT * DD;

    // ---------------- Phase 1: Q,K,V = x_b @ {Wq,Wk,Wv} ----------------
    floatx4 cq[2][4] = {};
    floatx4 ck[2][4] = {};
    floatx4 cv[2][4] = {};

    for (int kk = 0; kk < DD; kk += 32) {
        short8 a[2];
        #pragma unroll
        for (int mi = 0; mi < 2; ++mi) {
            int row = 32 * wave + 16 * mi + l16;
            a[mi] = cvt8(xb + row * DD + kk + quad * 8);
        }
        #pragma unroll
        for (int nt = 0; nt < 4; ++nt) {
            int n = 16 * nt + l16;
            short8 bq = *(const short8*)(wt + (0 * HH + n) * DD + kk + quad * 8);
            short8 bk = *(const short8*)(wt + (1 * HH + n) * DD + kk + quad * 8);
            short8 bv = *(const short8*)(wt + (2 * HH + n) * DD + kk + quad * 8);
            #pragma unroll
            for (int mi = 0; mi < 2; ++mi) {
                cq[mi][nt] = __builtin_amdgcn_mfma_f32_16x16x32_bf16(a[mi], bq, cq[mi][nt], 0, 0, 0);
                ck[mi][nt] = __builtin_amdgcn_mfma_f32_16x16x32_bf16(a[mi], bk, ck[mi][nt], 0, 0, 0);
                cv[mi][nt] = __builtin_amdgcn_mfma_f32_16x16x32_bf16(a[mi], bv, cv[mi][nt], 0, 0, 0);
            }
        }
    }

    // C-layout (col=l16, row=4*quad+reg) -> LDS. K row-major, V transposed, Q to wave scratch.
    unsigned short* qscr = Scr + wave * 32 * QS_STRIDE;
    #pragma unroll
    for (int mi = 0; mi < 2; ++mi)
      #pragma unroll
      for (int nt = 0; nt < 4; ++nt)
        #pragma unroll
        for (int r = 0; r < 4; ++r) {
            int rl = 16 * mi + 4 * quad + r;   // local row 0..31
            int col = 16 * nt + l16;           // 0..63
            qscr[rl * QS_STRIDE + col] = f2bf(cq[mi][nt][r]);
            int row = 32 * wave + rl;          // 0..255
            Ks[row * KS_STRIDE + col] = f2bf(ck[mi][nt][r]);
            Vt[col * VT_STRIDE + row] = f2bf(cv[mi][nt][r]);
        }

    __syncthreads();

    // Reload own Q rows as A-fragments (m=l16, k=quad*8+j).
    short8 aq[2][2];
    #pragma unroll
    for (int mi = 0; mi < 2; ++mi)
      #pragma unroll
      for (int ks = 0; ks < 2; ++ks)
        aq[mi][ks] = *(const short8*)(qscr + (16 * mi + l16) * QS_STRIDE + 32 * ks + quad * 8);

    // ---------------- Phase 2: flash-style causal attention ----------------
    floatx4 o[2][4] = {};
    float m_run[2][4], l_run[2][4];
    #pragma unroll
    for (int mi = 0; mi < 2; ++mi)
      #pragma unroll
      for (int r = 0; r < 4; ++r) { m_run[mi][r] = -1e30f; l_run[mi][r] = 0.f; }

    unsigned short* ps = Scr + wave * 32 * QS_STRIDE;  // reuse scratch (wave-private, no barrier)

    for (int c = 0; c <= wave; ++c) {           // key chunks of 32; causal => c <= wave
        floatx4 s[2][2] = {};
        #pragma unroll
        for (int ks = 0; ks < 2; ++ks) {
            #pragma unroll
            for (int ni = 0; ni < 2; ++ni) {
                short8 bk = *(const short8*)(Ks + (32 * c + 16 * ni + l16) * KS_STRIDE + 32 * ks + quad * 8);
                #pragma unroll
                for (int mi = 0; mi < 2; ++mi)
                    s[mi][ni] = __builtin_amdgcn_mfma_f32_16x16x32_bf16(aq[mi][ks], bk, s[mi][ni], 0, 0, 0);
            }
        }
        // scale + causal mask + online softmax (rows live in (quad,reg); cols across 16 lanes)
        #pragma unroll
        for (int mi = 0; mi < 2; ++mi) {
            #pragma unroll
            for (int r = 0; r < 4; ++r) {
                int row = 32 * wave + 16 * mi + 4 * quad + r;
                float v0 = s[mi][0][r] * SCALE;
                float v1 = s[mi][1][r] * SCALE;
                int c0 = 32 * c + l16;
                if (c0 > row) v0 = -1e30f;
                if (c0 + 16 > row) v1 = -1e30f;
                float t = fmaxf(v0, v1);
                t = fmaxf(t, __shfl_xor(t, 1));
                t = fmaxf(t, __shfl_xor(t, 2));
                t = fmaxf(t, __shfl_xor(t, 4));
                t = fmaxf(t, __shfl_xor(t, 8));
                float mn = fmaxf(m_run[mi][r], t);
                float alpha = __expf(m_run[mi][r] - mn);
                float p0 = __expf(v0 - mn);
                float p1 = __expf(v1 - mn);
                float rs = p0 + p1;
                rs += __shfl_xor(rs, 1);
                rs += __shfl_xor(rs, 2);
                rs += __shfl_xor(rs, 4);
                rs += __shfl_xor(rs, 8);
                l_run[mi][r] = l_run[mi][r] * alpha + rs;
                m_run[mi][r] = mn;
                #pragma unroll
                for (int nt = 0; nt < 4; ++nt) o[mi][nt][r] *= alpha;
                int rl = 16 * mi + 4 * quad + r;
                ps[rl * PS_STRIDE + l16] = f2bf(p0);
                ps[rl * PS_STRIDE + 16 + l16] = f2bf(p1);
            }
        }
        // P (C-layout) -> A-layout via wave-private LDS round trip, then O += P @ V_chunk
        short8 ap[2];
        #pragma unroll
        for (int mi = 0; mi < 2; ++mi)
            ap[mi] = *(const short8*)(ps + (16 * mi + l16) * PS_STRIDE + quad * 8);
        #pragma unroll
        for (int nt = 0; nt < 4; ++nt) {
            short8 bv = *(const short8*)(Vt + (16 * nt + l16) * VT_STRIDE + 32 * c + quad * 8);
            #pragma unroll
            for (int mi = 0; mi < 2; ++mi)
                o[mi][nt] = __builtin_amdgcn_mfma_f32_16x16x32_bf16(ap[mi], bv, o[mi][nt], 0, 0, 0);
        }
    }

    // ---------------- Epilogue: O / l, store fp32 ----------------
    float* outb = out + (size_t)b * TT * HH;
    #pragma unroll
    for (int mi = 0; mi < 2; ++mi)
      #pragma unroll
      for (int nt = 0; nt < 4; ++nt)
        #pragma unroll
        for (int r = 0; r < 4; ++r) {
            int row = 32 * wave + 16 * mi + 4 * quad + r;
            outb[row * HH + 16 * nt + l16] = o[mi][nt][r] / l_run[mi][r];
        }
}

extern "C" void kernel_launch(void* const* d_in, const int* in_sizes, int n_in,
                              void* d_out, int out_size, void* d_ws, size_t ws_size,
                              hipStream_t stream) {
    const float* x  = (const float*)d_in[0];
    const float* wq = (const float*)d_in[1];
    const float* wk = (const float*)d_in[2];
    const float* wv = (const float*)d_in[3];
    unsigned short* wt = (unsigned short*)d_ws;          // [3][H][D] bf16 = 147,456 B
    float* o = (float*)d_out;

    transpose_w_kernel<<<(3 * DD * HH + 255) / 256, 256, 0, stream>>>(wq, wk, wv, wt);
    attn_kernel<<<BATCH, 512, 0, stream>>>(x, wt, o);
}